// Round 1
// baseline (1136.873 us; speedup 1.0000x reference)
//
#include <hip/hip_runtime.h>

typedef short s16x8 __attribute__((ext_vector_type(8)));
typedef float f32x4 __attribute__((ext_vector_type(4)));

// ---------- helpers ----------
__device__ __forceinline__ unsigned short f2bf(float f) {
    unsigned int u = __builtin_bit_cast(unsigned int, f);
    u += 0x7fffu + ((u >> 16) & 1u);           // round-to-nearest-even
    return (unsigned short)(u >> 16);
}

__device__ __forceinline__ void gload16(const void* g, void* l) {
    __builtin_amdgcn_global_load_lds(
        (const __attribute__((address_space(1))) unsigned int*)g,
        (__attribute__((address_space(3))) unsigned int*)l,
        16, 0, 0);
}

// ---------- phase 1: fp32 -> bf16 casts ----------
__global__ void cast_bf16_kernel(const float* __restrict__ src,
                                 unsigned short* __restrict__ dst, int n4) {
    int i = blockIdx.x * 256 + threadIdx.x;
    if (i >= n4) return;
    float4 v = ((const float4*)src)[i];
    ushort4 o;
    o.x = f2bf(v.x); o.y = f2bf(v.y); o.z = f2bf(v.z); o.w = f2bf(v.w);
    ((ushort4*)dst)[i] = o;
}

// ---------- phase 2: gather relative position bias rpb[h][64][64] ----------
__global__ void rpb_kernel(const float* __restrict__ table,
                           const int* __restrict__ rel,
                           float* __restrict__ rpb) {
    int t = blockIdx.x * 64 + threadIdx.x;     // 0..4095  (i*64+j)
    int idx = rel[t];
#pragma unroll
    for (int h = 0; h < 16; ++h)
        rpb[h * 4096 + t] = table[idx * 16 + h];
}

// ---------- shared K-loop: 128x128 tile, K=512, BK=32 ----------
// SW=false: acc[i][j] rows = A-rows (tokens),  cols = B-rows (channels)
// SW=true : acc[j][i] rows = B-rows (channels), cols = A-rows (tokens)
//           (operand-swapped MFMA -> 4 consecutive CHANNELS per lane-reg-quad)
template <bool SW>
__device__ __forceinline__ void kloop128(const unsigned short* __restrict__ Ab,
                                         const unsigned short* __restrict__ Bb,
                                         unsigned short* Al, unsigned short* Bl,
                                         int t, int wave, int ln, int hk,
                                         int wr, int wc, f32x4 (&acc)[4][4]) {
    const int row = t >> 2, cg = t & 3;        // 16B chunk (row, col-group)
    for (int k0 = 0; k0 < 512; k0 += 32) {
        gload16(Ab + (size_t)row * 512 + k0 + cg * 8, &Al[wave * 512]);
        gload16(Ab + (size_t)(row + 64) * 512 + k0 + cg * 8, &Al[2048 + wave * 512]);
        gload16(Bb + (size_t)row * 512 + k0 + cg * 8, &Bl[wave * 512]);
        gload16(Bb + (size_t)(row + 64) * 512 + k0 + cg * 8, &Bl[2048 + wave * 512]);
        __syncthreads();
        s16x8 af[4], bf[4];
#pragma unroll
        for (int i = 0; i < 4; ++i)
            af[i] = *(const s16x8*)&Al[(wr + i * 16 + ln) * 32 + hk * 8];
#pragma unroll
        for (int j = 0; j < 4; ++j)
            bf[j] = *(const s16x8*)&Bl[(wc + j * 16 + ln) * 32 + hk * 8];
#pragma unroll
        for (int i = 0; i < 4; ++i)
#pragma unroll
            for (int j = 0; j < 4; ++j) {
                if constexpr (SW)
                    acc[j][i] = __builtin_amdgcn_mfma_f32_16x16x32_bf16(bf[j], af[i], acc[j][i], 0, 0, 0);
                else
                    acc[i][j] = __builtin_amdgcn_mfma_f32_16x16x32_bf16(af[i], bf[j], acc[i][j], 0, 0, 0);
            }
        __syncthreads();
    }
}

// ---------- GEMM C = A(MxK) * B(NxK)^T, bf16 in, fp32 acc ----------
// MODE 0: qkv projection. q/k blocks use swapped MFMA -> direct ushort4 stores
//         to [bh][tok][d]; v blocks use normal MFMA -> direct ushort4 stores
//         to v^T [bh][d][tok]. NO epilogue LDS repack.
// MODE 1: output projection, swapped MFMA -> float4 full-line fp32 stores.
template <int MODE, int NCOLS>
__global__ __launch_bounds__(256) void gemm_bt(
    const unsigned short* __restrict__ A, const unsigned short* __restrict__ B,
    const float* __restrict__ bq, const float* __restrict__ bv,
    unsigned short* __restrict__ qb, unsigned short* __restrict__ kb,
    unsigned short* __restrict__ vtb,
    const float* __restrict__ pb, float* __restrict__ out) {
    __shared__ unsigned short smem[8192];      // two 128x32 bf16 tiles
    unsigned short* Al = smem;
    unsigned short* Bl = smem + 4096;

    constexpr int NBN = NCOLS / 128;
    // XCD-chunked swizzle (grid % 8 == 0): all bn-tiles of a bm on one XCD
    const unsigned int cpx = gridDim.x >> 3;
    const unsigned int wg = (blockIdx.x & 7u) * cpx + (blockIdx.x >> 3);
    const int bm = wg / NBN;
    const int bn = wg % NBN;
    const int t = threadIdx.x;
    const int wave = t >> 6, lane = t & 63;
    const int ln = lane & 15, hk = lane >> 4;
    const int wr = (wave >> 1) * 64, wc = (wave & 1) * 64;

    const f32x4 zero = {0.f, 0.f, 0.f, 0.f};
    f32x4 acc[4][4];
#pragma unroll
    for (int i = 0; i < 4; ++i)
#pragma unroll
        for (int j = 0; j < 4; ++j) acc[i][j] = zero;

    const unsigned short* Ab = A + (size_t)bm * 128 * 512;
    const unsigned short* Bb = B + (size_t)bn * 128 * 512;

    if constexpr (MODE == 1) {
        kloop128<true>(Ab, Bb, Al, Bl, t, wave, ln, hk, wr, wc, acc);
        // lane-reg-quad = 4 consecutive output channels at one token
#pragma unroll
        for (int j = 0; j < 4; ++j) {
            const int nn0 = bn * 128 + wc + j * 16 + hk * 4;   // 4-aligned channel
            const float4 b4 = *(const float4*)&pb[nn0];
#pragma unroll
            for (int i = 0; i < 4; ++i) {
                const int m = bm * 128 + wr + i * 16 + ln;     // token row
                float4 o4;
                o4.x = acc[j][i][0] + b4.x;
                o4.y = acc[j][i][1] + b4.y;
                o4.z = acc[j][i][2] + b4.z;
                o4.w = acc[j][i][3] + b4.w;
                *(float4*)(out + (size_t)m * NCOLS + nn0) = o4;
            }
        }
    } else {
        const int which = bn >> 2;             // 0=q, 1=k, 2=v
        const int bb = bm * 2;                 // tile spans windows bb, bb+1
        if (which < 2) {
            // swapped: regs = 4 consecutive d-channels, lane col = token
            kloop128<true>(Ab, Bb, Al, Bl, t, wave, ln, hk, wr, wc, acc);
            unsigned short* dst0 = (which == 0) ? qb : kb;
#pragma unroll
            for (int j = 0; j < 4; ++j) {
                const int colT0 = wc + j * 16 + hk * 4;
                const int rem0 = (bn * 128 + colT0) & 511;     // channel in section
                float4 b4 = {0.f, 0.f, 0.f, 0.f};
                if (which == 0) b4 = *(const float4*)&bq[rem0];
                const int head = rem0 >> 5;
                const int dd0 = rem0 & 31;                     // 4-aligned
#pragma unroll
                for (int i = 0; i < 4; ++i) {
                    const int tokL = wr + i * 16 + ln;         // 0..127
                    const size_t bh = (size_t)((bb + (tokL >> 6)) * 16 + head);
                    ushort4 pk;
                    pk.x = f2bf(acc[j][i][0] + b4.x);
                    pk.y = f2bf(acc[j][i][1] + b4.y);
                    pk.z = f2bf(acc[j][i][2] + b4.z);
                    pk.w = f2bf(acc[j][i][3] + b4.w);
                    *(ushort4*)(dst0 + bh * 2048 + (size_t)(tokL & 63) * 32 + dd0) = pk;
                }
            }
        } else {
            // normal: regs = 4 consecutive tokens at one d-channel -> v^T layout
            kloop128<false>(Ab, Bb, Al, Bl, t, wave, ln, hk, wr, wc, acc);
#pragma unroll
            for (int i = 0; i < 4; ++i) {
                const int tok0L = wr + i * 16 + hk * 4;        // 4-aligned token
                const size_t bhbase = (size_t)(bb + (tok0L >> 6)) * 16;
                const int tok0 = tok0L & 63;
#pragma unroll
                for (int j = 0; j < 4; ++j) {
                    const int rem = (bn * 128 + wc + j * 16 + ln) & 511;
                    const float bias = bv[rem];
                    const int head = rem >> 5, dd = rem & 31;
                    ushort4 pk;
                    pk.x = f2bf(acc[i][j][0] + bias);
                    pk.y = f2bf(acc[i][j][1] + bias);
                    pk.z = f2bf(acc[i][j][2] + bias);
                    pk.w = f2bf(acc[i][j][3] + bias);
                    *(ushort4*)(vtb + (bhbase + head) * 2048 + (size_t)dd * 64 + tok0) = pk;
                }
            }
        }
    }
}

// ---------- phase 4: attention, one block per (b, head) ----------
__global__ __launch_bounds__(256) void attn_kernel(
    const unsigned short* __restrict__ qbuf, const unsigned short* __restrict__ kbuf,
    const unsigned short* __restrict__ vtbuf, const float* __restrict__ rpb,
    const float* __restrict__ mask, unsigned short* __restrict__ aout) {
    __shared__ unsigned short ql[64 * 32];   // Q [tok][d]
    __shared__ unsigned short kl[64 * 32];   // K [tok][d]
    __shared__ unsigned short vl[32 * 64];   // V^T [d][tok]
    __shared__ unsigned short plds[64 * 64]; // P bf16 [row][col]

    const int bh = blockIdx.x;
    const int b = bh >> 4, head = bh & 15;
    const int wmask = b & 255;               // window index = b % NW
    const int t = threadIdx.x, wave = t >> 6, lane = t & 63;
    const int ln = lane & 15, hk = lane >> 4;

    const size_t base = (size_t)bh * 2048;
    gload16(qbuf + base + t * 8, &ql[wave * 512]);
    gload16(kbuf + base + t * 8, &kl[wave * 512]);
    gload16(vtbuf + base + t * 8, &vl[wave * 512]);
    __syncthreads();

    // S = Q K^T : wave handles rows [16*wave, 16*wave+16)
    const f32x4 zero = {0.f, 0.f, 0.f, 0.f};
    s16x8 aq = *(const s16x8*)&ql[(wave * 16 + ln) * 32 + hk * 8];
    f32x4 sc[4];
#pragma unroll
    for (int j = 0; j < 4; ++j) {
        s16x8 bk = *(const s16x8*)&kl[(j * 16 + ln) * 32 + hk * 8];
        sc[j] = __builtin_amdgcn_mfma_f32_16x16x32_bf16(aq, bk, zero, 0, 0, 0);
    }

    const float scale = 0.17677669529663687f;  // 32^-0.5
    const float* rpb_h = rpb + head * 4096;
    const float* msk = mask + wmask * 4096;

    float p[4][4];
#pragma unroll
    for (int r = 0; r < 4; ++r) {
        const int i = wave * 16 + hk * 4 + r;
        float v[4], m = -1e30f;
#pragma unroll
        for (int j = 0; j < 4; ++j) {
            const int c = j * 16 + ln;
            v[j] = sc[j][r] * scale + rpb_h[i * 64 + c] + msk[i * 64 + c];
            m = fmaxf(m, v[j]);
        }
        for (int off = 1; off < 16; off <<= 1) m = fmaxf(m, __shfl_xor(m, off));
        float s = 0.f;
#pragma unroll
        for (int j = 0; j < 4; ++j) { v[j] = __expf(v[j] - m); s += v[j]; }
        for (int off = 1; off < 16; off <<= 1) s += __shfl_xor(s, off);
        const float inv = 1.f / s;
#pragma unroll
        for (int j = 0; j < 4; ++j) p[r][j] = v[j] * inv;
    }
    // C-layout -> A-operand layout round trip through LDS
#pragma unroll
    for (int r = 0; r < 4; ++r)
#pragma unroll
        for (int j = 0; j < 4; ++j)
            plds[(wave * 16 + hk * 4 + r) * 64 + j * 16 + ln] = f2bf(p[r][j]);
    __syncthreads();

    // O^T = (P V)^T via swapped operands: regs = 4 consecutive d at one token
    f32x4 o2[2] = {zero, zero};
#pragma unroll
    for (int kt = 0; kt < 2; ++kt) {
        s16x8 ap = *(const s16x8*)&plds[(wave * 16 + ln) * 64 + kt * 32 + hk * 8];
#pragma unroll
        for (int nt = 0; nt < 2; ++nt) {
            s16x8 bvf = *(const s16x8*)&vl[(nt * 16 + ln) * 64 + kt * 32 + hk * 8];
            o2[nt] = __builtin_amdgcn_mfma_f32_16x16x32_bf16(bvf, ap, o2[nt], 0, 0, 0);
        }
    }
    // store attn_out as [b, tok, head*32+dd] bf16, packed ushort4 per lane
#pragma unroll
    for (int nt = 0; nt < 2; ++nt) {
        ushort4 pk;
        pk.x = f2bf(o2[nt][0]); pk.y = f2bf(o2[nt][1]);
        pk.z = f2bf(o2[nt][2]); pk.w = f2bf(o2[nt][3]);
        *(ushort4*)(aout + ((size_t)(b * 64 + wave * 16 + ln)) * 512
                    + head * 32 + nt * 16 + hk * 4) = pk;
    }
}

// ---------- launcher ----------
extern "C" void kernel_launch(void* const* d_in, const int* in_sizes, int n_in,
                              void* d_out, int out_size, void* d_ws, size_t ws_size,
                              hipStream_t stream) {
    const float* x      = (const float*)d_in[0];
    const float* mask   = (const float*)d_in[1];
    const float* qkv_w  = (const float*)d_in[2];
    const float* q_bias = (const float*)d_in[3];
    const float* v_bias = (const float*)d_in[4];
    const float* rpb_t  = (const float*)d_in[5];
    const float* proj_w = (const float*)d_in[6];
    const float* proj_b = (const float*)d_in[7];
    const int*   rel    = (const int*)d_in[8];
    float* out = (float*)d_out;

    char* ws = (char*)d_ws;
    unsigned short* xbf   = (unsigned short*)ws;                  // 128 MiB, reused as attn_out
    unsigned short* qbuf  = (unsigned short*)(ws + 0x08000000);   // 128 MiB
    unsigned short* kbuf  = (unsigned short*)(ws + 0x10000000);   // 128 MiB
    unsigned short* vtbuf = (unsigned short*)(ws + 0x18000000);   // 128 MiB
    unsigned short* wqkv  = (unsigned short*)(ws + 0x20000000);   // 1.5 MiB
    unsigned short* wproj = (unsigned short*)(ws + 0x20180000);   // 0.5 MiB
    float*          rpb   = (float*)(ws + 0x20200000);            // 0.25 MiB
    unsigned short* aout  = xbf;

    cast_bf16_kernel<<<65536, 256, 0, stream>>>(x, xbf, 16777216);
    cast_bf16_kernel<<<768, 256, 0, stream>>>(qkv_w, wqkv, 196608);
    cast_bf16_kernel<<<256, 256, 0, stream>>>(proj_w, wproj, 65536);
    rpb_kernel<<<64, 64, 0, stream>>>(rpb_t, rel, rpb);

    gemm_bt<0, 1536><<<1024 * 12, 256, 0, stream>>>(
        xbf, wqkv, q_bias, v_bias, qbuf, kbuf, vtbuf, nullptr, nullptr);

    attn_kernel<<<32768, 256, 0, stream>>>(qbuf, kbuf, vtbuf, rpb, mask, aout);

    gemm_bt<1, 512><<<1024 * 4, 256, 0, stream>>>(
        aout, wproj, nullptr, nullptr, nullptr, nullptr, nullptr, proj_b, out);
}

// Round 2
// 1060.894 us; speedup vs baseline: 1.0716x; 1.0716x over previous
//
#include <hip/hip_runtime.h>

typedef short s16x8 __attribute__((ext_vector_type(8)));
typedef float f32x4 __attribute__((ext_vector_type(4)));

// ---------- helpers ----------
__device__ __forceinline__ unsigned short f2bf(float f) {
    unsigned int u = __builtin_bit_cast(unsigned int, f);
    u += 0x7fffu + ((u >> 16) & 1u);           // round-to-nearest-even
    return (unsigned short)(u >> 16);
}

__device__ __forceinline__ void gload16(const void* g, void* l) {
    __builtin_amdgcn_global_load_lds(
        (const __attribute__((address_space(1))) unsigned int*)g,
        (__attribute__((address_space(3))) unsigned int*)l,
        16, 0, 0);
}

// ---------- phase 1: fp32 -> bf16 casts ----------
__global__ void cast_bf16_kernel(const float* __restrict__ src,
                                 unsigned short* __restrict__ dst, int n4) {
    int i = blockIdx.x * 256 + threadIdx.x;
    if (i >= n4) return;
    float4 v = ((const float4*)src)[i];
    ushort4 o;
    o.x = f2bf(v.x); o.y = f2bf(v.y); o.z = f2bf(v.z); o.w = f2bf(v.w);
    ((ushort4*)dst)[i] = o;
}

// ---------- phase 2: gather relative position bias rpb[h][64][64] ----------
__global__ void rpb_kernel(const float* __restrict__ table,
                           const int* __restrict__ rel,
                           float* __restrict__ rpb) {
    int t = blockIdx.x * 64 + threadIdx.x;     // 0..4095  (i*64+j)
    int idx = rel[t];
#pragma unroll
    for (int h = 0; h < 16; ++h)
        rpb[h * 4096 + t] = table[idx * 16 + h];
}

// ---------- shared K-loop: 128x128 tile, K=512, BK=32 ----------
// SW=false: acc[i][j] regs = 4 consecutive A-rows (tokens) at one B-row
// SW=true : acc[j][i] regs = 4 consecutive B-rows (channels) at one A-row
template <bool SW>
__device__ __forceinline__ void kloop128(const unsigned short* __restrict__ Ab,
                                         const unsigned short* __restrict__ Bb,
                                         unsigned short* Al, unsigned short* Bl,
                                         int t, int wave, int ln, int hk,
                                         int wr, int wc, f32x4 (&acc)[4][4]) {
    const int row = t >> 2, cg = t & 3;        // 16B chunk (row, col-group)
    for (int k0 = 0; k0 < 512; k0 += 32) {
        gload16(Ab + (size_t)row * 512 + k0 + cg * 8, &Al[wave * 512]);
        gload16(Ab + (size_t)(row + 64) * 512 + k0 + cg * 8, &Al[2048 + wave * 512]);
        gload16(Bb + (size_t)row * 512 + k0 + cg * 8, &Bl[wave * 512]);
        gload16(Bb + (size_t)(row + 64) * 512 + k0 + cg * 8, &Bl[2048 + wave * 512]);
        __syncthreads();
        s16x8 af[4], bf[4];
#pragma unroll
        for (int i = 0; i < 4; ++i)
            af[i] = *(const s16x8*)&Al[(wr + i * 16 + ln) * 32 + hk * 8];
#pragma unroll
        for (int j = 0; j < 4; ++j)
            bf[j] = *(const s16x8*)&Bl[(wc + j * 16 + ln) * 32 + hk * 8];
#pragma unroll
        for (int i = 0; i < 4; ++i)
#pragma unroll
            for (int j = 0; j < 4; ++j) {
                if constexpr (SW)
                    acc[j][i] = __builtin_amdgcn_mfma_f32_16x16x32_bf16(bf[j], af[i], acc[j][i], 0, 0, 0);
                else
                    acc[i][j] = __builtin_amdgcn_mfma_f32_16x16x32_bf16(af[i], bf[j], acc[i][j], 0, 0, 0);
            }
        __syncthreads();
    }
}

// ---------- GEMM C = A(MxK) * B(NxK)^T, bf16 in, fp32 acc ----------
// Epilogues: swapped/normal MFMA keeps data packed in regs; a barrier-free
// per-wave-private LDS repack (reusing staging smem after the final K-loop
// barrier) turns the scattered C-fragment layout into fully coalesced
// 16B/lane global stores.
template <int MODE, int NCOLS>
__global__ __launch_bounds__(256) void gemm_bt(
    const unsigned short* __restrict__ A, const unsigned short* __restrict__ B,
    const float* __restrict__ bq, const float* __restrict__ bv,
    unsigned short* __restrict__ qb, unsigned short* __restrict__ kb,
    unsigned short* __restrict__ vtb,
    const float* __restrict__ pb, float* __restrict__ out) {
    // K-loop uses smem[0..8191] (two 128x32 tiles); epilogue reuses the whole
    // buffer as 4 x 2560-short wave-private repack regions (no barrier needed:
    // the K-loop ends with __syncthreads and regions are wave-private).
    __shared__ __align__(16) unsigned short smem[10240];
    unsigned short* Al = smem;
    unsigned short* Bl = smem + 4096;

    constexpr int NBN = NCOLS / 128;
    // XCD-chunked swizzle (grid % 8 == 0): all bn-tiles of a bm on one XCD
    const unsigned int cpx = gridDim.x >> 3;
    const unsigned int wg = (blockIdx.x & 7u) * cpx + (blockIdx.x >> 3);
    const int bm = wg / NBN;
    const int bn = wg % NBN;
    const int t = threadIdx.x;
    const int wave = t >> 6, lane = t & 63;
    const int ln = lane & 15, hk = lane >> 4;
    const int wr = (wave >> 1) * 64, wc = (wave & 1) * 64;

    const f32x4 zero = {0.f, 0.f, 0.f, 0.f};
    f32x4 acc[4][4];
#pragma unroll
    for (int i = 0; i < 4; ++i)
#pragma unroll
        for (int j = 0; j < 4; ++j) acc[i][j] = zero;

    const unsigned short* Ab = A + (size_t)bm * 128 * 512;
    const unsigned short* Bb = B + (size_t)bn * 128 * 512;

    if constexpr (MODE == 1) {
        kloop128<true>(Ab, Bb, Al, Bl, t, wave, ln, hk, wr, wc, acc);
        // per-wave fp32 region [64 tok][20 words] (pad 16->20 kills conflicts)
        float* epf = (float*)smem + wave * 1280;
#pragma unroll
        for (int j = 0; j < 4; ++j) {
            const int nn0 = bn * 128 + wc + j * 16 + hk * 4;
            const float4 b4 = *(const float4*)&pb[nn0];
#pragma unroll
            for (int i = 0; i < 4; ++i) {
                const int tk = i * 16 + ln;
                float4 o4;
                o4.x = acc[j][i][0] + b4.x;
                o4.y = acc[j][i][1] + b4.y;
                o4.z = acc[j][i][2] + b4.z;
                o4.w = acc[j][i][3] + b4.w;
                *(float4*)&epf[tk * 20 + hk * 4] = o4;
            }
            const int nnb = bn * 128 + wc + j * 16;
#pragma unroll
            for (int rr = 0; rr < 4; ++rr) {
                const int li = rr * 64 + lane;
                const int tk = li >> 2, c4 = (li & 3) * 4;
                float4 v4 = *(const float4*)&epf[tk * 20 + c4];
                *(float4*)(out + (size_t)(bm * 128 + wr + tk) * NCOLS + nnb + c4) = v4;
            }
        }
    } else {
        const int which = bn >> 2;             // 0=q, 1=k, 2=v
        const int bb = bm * 2;                 // tile spans windows bb, bb+1
        const size_t winbase = (size_t)((bb + (wr >> 6)) * 16);
        unsigned short* ep = smem + wave * 2560;
        if (which < 2) {
            // swapped: regs = 4 consecutive d-channels at one token
            kloop128<true>(Ab, Bb, Al, Bl, t, wave, ln, hk, wr, wc, acc);
            unsigned short* dst0 = (which == 0) ? qb : kb;
            // region [64 tok][40 shorts] (32 used): conflict-free writes
#pragma unroll
            for (int H = 0; H < 2; ++H) {
#pragma unroll
                for (int j2 = 0; j2 < 2; ++j2) {
                    const int j = H * 2 + j2;
                    const int rem0 = (bn * 128 + wc + j * 16 + hk * 4) & 511;
                    float4 b4 = {0.f, 0.f, 0.f, 0.f};
                    if (which == 0) b4 = *(const float4*)&bq[rem0];
                    const int ch0 = j2 * 16 + hk * 4;
#pragma unroll
                    for (int i = 0; i < 4; ++i) {
                        const int tk = i * 16 + ln;
                        ushort4 pk;
                        pk.x = f2bf(acc[j][i][0] + b4.x);
                        pk.y = f2bf(acc[j][i][1] + b4.y);
                        pk.z = f2bf(acc[j][i][2] + b4.z);
                        pk.w = f2bf(acc[j][i][3] + b4.w);
                        *(ushort4*)&ep[tk * 40 + ch0] = pk;
                    }
                }
                const int remH = (bn * 128 + wc + H * 32) & 511;
                const size_t Dq = (winbase + (remH >> 5)) * 2048;
#pragma unroll
                for (int rr = 0; rr < 4; ++rr) {      // 1KB contiguous / wave-instr
                    const int li = rr * 64 + lane;
                    const int tk = li >> 2, c8 = (li & 3) * 8;
                    s16x8 val = *(const s16x8*)&ep[tk * 40 + c8];
                    *(s16x8*)(dst0 + Dq + tk * 32 + c8) = val;
                }
            }
        } else {
            // normal: regs = 4 consecutive tokens at one d-channel -> v^T
            kloop128<false>(Ab, Bb, Al, Bl, t, wave, ln, hk, wr, wc, acc);
            // region [32 ch][72 shorts] (64 used)
#pragma unroll
            for (int H = 0; H < 2; ++H) {
#pragma unroll
                for (int j2 = 0; j2 < 2; ++j2) {
                    const int j = H * 2 + j2;
                    const int rem = (bn * 128 + wc + j * 16 + ln) & 511;
                    const float bias = bv[rem];
                    const int ch = j2 * 16 + ln;
#pragma unroll
                    for (int i = 0; i < 4; ++i) {
                        const int tk = i * 16 + hk * 4;
                        ushort4 pk;
                        pk.x = f2bf(acc[i][j][0] + bias);
                        pk.y = f2bf(acc[i][j][1] + bias);
                        pk.z = f2bf(acc[i][j][2] + bias);
                        pk.w = f2bf(acc[i][j][3] + bias);
                        *(ushort4*)&ep[ch * 72 + tk] = pk;
                    }
                }
                const int remH = (bn * 128 + wc + H * 32) & 511;
                const size_t Dv = (winbase + (remH >> 5)) * 2048;
#pragma unroll
                for (int rr = 0; rr < 4; ++rr) {      // 1KB contiguous / wave-instr
                    const int li = rr * 64 + lane;
                    const int dd = li >> 3, t8 = (li & 7) * 8;
                    s16x8 val = *(const s16x8*)&ep[dd * 72 + t8];
                    *(s16x8*)(vtb + Dv + dd * 64 + t8) = val;
                }
            }
        }
    }
}

// ---------- phase 4: attention, one block per (b, head) ----------
__global__ __launch_bounds__(256) void attn_kernel(
    const unsigned short* __restrict__ qbuf, const unsigned short* __restrict__ kbuf,
    const unsigned short* __restrict__ vtbuf, const float* __restrict__ rpb,
    const float* __restrict__ mask, unsigned short* __restrict__ aout) {
    __shared__ __align__(16) unsigned short ql[64 * 32];   // Q [tok][d]
    __shared__ __align__(16) unsigned short kl[64 * 32];   // K [tok][d]
    __shared__ __align__(16) unsigned short vl[32 * 64];   // V^T [d][tok]
    __shared__ __align__(16) unsigned short plds[64 * 72]; // P bf16, padded stride

    const int bh = blockIdx.x;
    const int b = bh >> 4, head = bh & 15;
    const int wmask = b & 255;               // window index = b % NW
    const int t = threadIdx.x, wave = t >> 6, lane = t & 63;
    const int ln = lane & 15, hk = lane >> 4;

    const size_t base = (size_t)bh * 2048;
    gload16(qbuf + base + t * 8, &ql[wave * 512]);
    gload16(kbuf + base + t * 8, &kl[wave * 512]);
    gload16(vtbuf + base + t * 8, &vl[wave * 512]);
    __syncthreads();

    // S = Q K^T : wave handles rows [16*wave, 16*wave+16)
    const f32x4 zero = {0.f, 0.f, 0.f, 0.f};
    s16x8 aq = *(const s16x8*)&ql[(wave * 16 + ln) * 32 + hk * 8];
    f32x4 sc[4];
#pragma unroll
    for (int j = 0; j < 4; ++j) {
        s16x8 bk = *(const s16x8*)&kl[(j * 16 + ln) * 32 + hk * 8];
        sc[j] = __builtin_amdgcn_mfma_f32_16x16x32_bf16(aq, bk, zero, 0, 0, 0);
    }

    const float scale = 0.17677669529663687f;  // 32^-0.5
    const float* rpb_h = rpb + head * 4096;
    const float* msk = mask + wmask * 4096;

    float p[4][4];
#pragma unroll
    for (int r = 0; r < 4; ++r) {
        const int i = wave * 16 + hk * 4 + r;
        float v[4], m = -1e30f;
#pragma unroll
        for (int j = 0; j < 4; ++j) {
            const int c = j * 16 + ln;
            v[j] = sc[j][r] * scale + rpb_h[i * 64 + c] + msk[i * 64 + c];
            m = fmaxf(m, v[j]);
        }
        for (int off = 1; off < 16; off <<= 1) m = fmaxf(m, __shfl_xor(m, off));
        float s = 0.f;
#pragma unroll
        for (int j = 0; j < 4; ++j) { v[j] = __expf(v[j] - m); s += v[j]; }
        for (int off = 1; off < 16; off <<= 1) s += __shfl_xor(s, off);
        const float inv = 1.f / s;
#pragma unroll
        for (int j = 0; j < 4; ++j) p[r][j] = v[j] * inv;
    }
    // P rows are wave-private (write rows wave*16+hk*4+r, read rows
    // wave*16+ln) -> no barrier needed; in-wave lgkmcnt orders the LDS ops.
#pragma unroll
    for (int r = 0; r < 4; ++r)
#pragma unroll
        for (int j = 0; j < 4; ++j)
            plds[(wave * 16 + hk * 4 + r) * 72 + j * 16 + ln] = f2bf(p[r][j]);

    // O^T = (P V)^T via swapped operands: regs = 4 consecutive d at one token
    f32x4 o2[2] = {zero, zero};
#pragma unroll
    for (int kt = 0; kt < 2; ++kt) {
        s16x8 ap = *(const s16x8*)&plds[(wave * 16 + ln) * 72 + kt * 32 + hk * 8];
#pragma unroll
        for (int nt = 0; nt < 2; ++nt) {
            s16x8 bvf = *(const s16x8*)&vl[(nt * 16 + ln) * 64 + kt * 32 + hk * 8];
            o2[nt] = __builtin_amdgcn_mfma_f32_16x16x32_bf16(bvf, ap, o2[nt], 0, 0, 0);
        }
    }
    // coalesce aout stores through a wave-private slice of plds
    unsigned short* ep = plds + wave * 1152;   // rows wave*16.. (own rows)
#pragma unroll
    for (int nt = 0; nt < 2; ++nt) {
        ushort4 pk;
        pk.x = f2bf(o2[nt][0]); pk.y = f2bf(o2[nt][1]);
        pk.z = f2bf(o2[nt][2]); pk.w = f2bf(o2[nt][3]);
        *(ushort4*)&ep[ln * 40 + nt * 16 + hk * 4] = pk;
    }
    const int tk = lane >> 2, c8 = (lane & 3) * 8;
    s16x8 val = *(const s16x8*)&ep[tk * 40 + c8];
    *(s16x8*)(aout + ((size_t)(b * 64 + wave * 16 + tk)) * 512 + head * 32 + c8) = val;
}

// ---------- launcher ----------
extern "C" void kernel_launch(void* const* d_in, const int* in_sizes, int n_in,
                              void* d_out, int out_size, void* d_ws, size_t ws_size,
                              hipStream_t stream) {
    const float* x      = (const float*)d_in[0];
    const float* mask   = (const float*)d_in[1];
    const float* qkv_w  = (const float*)d_in[2];
    const float* q_bias = (const float*)d_in[3];
    const float* v_bias = (const float*)d_in[4];
    const float* rpb_t  = (const float*)d_in[5];
    const float* proj_w = (const float*)d_in[6];
    const float* proj_b = (const float*)d_in[7];
    const int*   rel    = (const int*)d_in[8];
    float* out = (float*)d_out;

    char* ws = (char*)d_ws;
    unsigned short* xbf   = (unsigned short*)ws;                  // 128 MiB, reused as attn_out
    unsigned short* qbuf  = (unsigned short*)(ws + 0x08000000);   // 128 MiB
    unsigned short* kbuf  = (unsigned short*)(ws + 0x10000000);   // 128 MiB
    unsigned short* vtbuf = (unsigned short*)(ws + 0x18000000);   // 128 MiB
    unsigned short* wqkv  = (unsigned short*)(ws + 0x20000000);   // 1.5 MiB
    unsigned short* wproj = (unsigned short*)(ws + 0x20180000);   // 0.5 MiB
    float*          rpb   = (float*)(ws + 0x20200000);            // 0.25 MiB
    unsigned short* aout  = xbf;

    cast_bf16_kernel<<<65536, 256, 0, stream>>>(x, xbf, 16777216);
    cast_bf16_kernel<<<768, 256, 0, stream>>>(qkv_w, wqkv, 196608);
    cast_bf16_kernel<<<256, 256, 0, stream>>>(proj_w, wproj, 65536);
    rpb_kernel<<<64, 64, 0, stream>>>(rpb_t, rel, rpb);

    gemm_bt<0, 1536><<<1024 * 12, 256, 0, stream>>>(
        xbf, wqkv, q_bias, v_bias, qbuf, kbuf, vtbuf, nullptr, nullptr);

    attn_kernel<<<32768, 256, 0, stream>>>(qbuf, kbuf, vtbuf, rpb, mask, aout);

    gemm_bt<1, 512><<<1024 * 4, 256, 0, stream>>>(
        aout, wproj, nullptr, nullptr, nullptr, nullptr, nullptr, proj_b, out);
}

// Round 3
// 1012.337 us; speedup vs baseline: 1.1230x; 1.0480x over previous
//
#include <hip/hip_runtime.h>

typedef short s16x8 __attribute__((ext_vector_type(8)));
typedef float f32x4 __attribute__((ext_vector_type(4)));

// ---------- helpers ----------
__device__ __forceinline__ unsigned short f2bf(float f) {
    unsigned int u = __builtin_bit_cast(unsigned int, f);
    u += 0x7fffu + ((u >> 16) & 1u);           // round-to-nearest-even
    return (unsigned short)(u >> 16);
}

__device__ __forceinline__ void gload16(const void* g, void* l) {
    __builtin_amdgcn_global_load_lds(
        (const __attribute__((address_space(1))) unsigned int*)g,
        (__attribute__((address_space(3))) unsigned int*)l,
        16, 0, 0);
}

// ---------- phase 1: fp32 -> bf16 casts ----------
__global__ void cast_bf16_kernel(const float* __restrict__ src,
                                 unsigned short* __restrict__ dst, int n4) {
    int i = blockIdx.x * 256 + threadIdx.x;
    if (i >= n4) return;
    float4 v = ((const float4*)src)[i];
    ushort4 o;
    o.x = f2bf(v.x); o.y = f2bf(v.y); o.z = f2bf(v.z); o.w = f2bf(v.w);
    ((ushort4*)dst)[i] = o;
}

// ---------- phase 2: gather relative position bias rpb[h][64][64] ----------
__global__ void rpb_kernel(const float* __restrict__ table,
                           const int* __restrict__ rel,
                           float* __restrict__ rpb) {
    int t = blockIdx.x * 64 + threadIdx.x;     // 0..4095  (i*64+j)
    int idx = rel[t];
#pragma unroll
    for (int h = 0; h < 16; ++h)
        rpb[h * 4096 + t] = table[idx * 16 + h];
}

// ---------- K-loop building blocks ----------
__device__ __forceinline__ void stage_step(const unsigned short* __restrict__ Ab,
                                           const unsigned short* __restrict__ Bb,
                                           unsigned short* base, int wave,
                                           size_t gA0, size_t gA1, int k0) {
    gload16(Ab + gA0 + k0, &base[wave * 512]);
    gload16(Ab + gA1 + k0, &base[2048 + wave * 512]);
    gload16(Bb + gA0 + k0, &base[4096 + wave * 512]);
    gload16(Bb + gA1 + k0, &base[6144 + wave * 512]);
}

template <bool SW>
__device__ __forceinline__ void mfma_step(const unsigned short* base, int ln, int hk,
                                          int wr, int wc, f32x4 (&acc)[4][4]) {
    const unsigned short* Al = base;
    const unsigned short* Bl = base + 4096;
    s16x8 af[4], bf[4];
#pragma unroll
    for (int i = 0; i < 4; ++i)
        af[i] = *(const s16x8*)&Al[(wr + i * 16 + ln) * 32 + hk * 8];
#pragma unroll
    for (int j = 0; j < 4; ++j)
        bf[j] = *(const s16x8*)&Bl[(wc + j * 16 + ln) * 32 + hk * 8];
#pragma unroll
    for (int i = 0; i < 4; ++i)
#pragma unroll
        for (int j = 0; j < 4; ++j) {
            if constexpr (SW)
                acc[j][i] = __builtin_amdgcn_mfma_f32_16x16x32_bf16(bf[j], af[i], acc[j][i], 0, 0, 0);
            else
                acc[i][j] = __builtin_amdgcn_mfma_f32_16x16x32_bf16(af[i], bf[j], acc[i][j], 0, 0, 0);
        }
}

// Double-buffered 128x128 K-loop (K=512, BK=32): stage tile t+1 while
// computing tile t; ONE __syncthreads per K-step, whose implicit vmcnt(0)
// drain lands after a full compute phase of overlap (T3 minimum-2-phase).
// Buffer-reuse safety: all ds_reads of a buffer are consumed by MFMAs
// before each wave reaches the barrier that precedes the overwrite.
template <bool SW>
__device__ __forceinline__ void kloop128(const unsigned short* __restrict__ Ab,
                                         const unsigned short* __restrict__ Bb,
                                         unsigned short* smem,
                                         int t, int wave, int ln, int hk,
                                         int wr, int wc, f32x4 (&acc)[4][4]) {
    const int row = t >> 2, cg = t & 3;
    const size_t gA0 = (size_t)row * 512 + cg * 8;
    const size_t gA1 = (size_t)(row + 64) * 512 + cg * 8;
    unsigned short* b0 = smem;          // tiles A,B for even steps
    unsigned short* b1 = smem + 8192;   // tiles A,B for odd steps

    stage_step(Ab, Bb, b0, wave, gA0, gA1, 0);
    __syncthreads();
    for (int k0 = 0; k0 < 512; k0 += 64) {
        stage_step(Ab, Bb, b1, wave, gA0, gA1, k0 + 32);
        mfma_step<SW>(b0, ln, hk, wr, wc, acc);
        __syncthreads();
        if (k0 + 64 < 512)
            stage_step(Ab, Bb, b0, wave, gA0, gA1, k0 + 64);
        mfma_step<SW>(b1, ln, hk, wr, wc, acc);
        __syncthreads();
    }
}

// ---------- GEMM C = A(MxK) * B(NxK)^T, bf16 in, fp32 acc ----------
// Epilogues: swapped/normal MFMA keeps data packed in regs; a barrier-free
// per-wave-private LDS repack (reusing staging smem after the final K-loop
// barrier) turns the scattered C-fragment layout into fully coalesced
// 16B/lane global stores.
template <int MODE, int NCOLS>
__global__ __launch_bounds__(256) void gemm_bt(
    const unsigned short* __restrict__ A, const unsigned short* __restrict__ B,
    const float* __restrict__ bq, const float* __restrict__ bv,
    unsigned short* __restrict__ qb, unsigned short* __restrict__ kb,
    unsigned short* __restrict__ vtb,
    const float* __restrict__ pb, float* __restrict__ out) {
    // 32KB: double-buffered staging (2 x 8192 shorts); epilogue reuses it as
    // 4 x 2560-short wave-private repack regions (safe: post final barrier,
    // regions wave-private).
    __shared__ __align__(16) unsigned short smem[16384];

    constexpr int NBN = NCOLS / 128;
    // XCD-chunked swizzle (grid % 8 == 0): all bn-tiles of a bm on one XCD
    const unsigned int cpx = gridDim.x >> 3;
    const unsigned int wg = (blockIdx.x & 7u) * cpx + (blockIdx.x >> 3);
    const int bm = wg / NBN;
    const int bn = wg % NBN;
    const int t = threadIdx.x;
    const int wave = t >> 6, lane = t & 63;
    const int ln = lane & 15, hk = lane >> 4;
    const int wr = (wave >> 1) * 64, wc = (wave & 1) * 64;

    const f32x4 zero = {0.f, 0.f, 0.f, 0.f};
    f32x4 acc[4][4];
#pragma unroll
    for (int i = 0; i < 4; ++i)
#pragma unroll
        for (int j = 0; j < 4; ++j) acc[i][j] = zero;

    const unsigned short* Ab = A + (size_t)bm * 128 * 512;
    const unsigned short* Bb = B + (size_t)bn * 128 * 512;

    if constexpr (MODE == 1) {
        kloop128<true>(Ab, Bb, smem, t, wave, ln, hk, wr, wc, acc);
        // per-wave fp32 region [64 tok][20 words] (pad 16->20 kills conflicts)
        float* epf = (float*)smem + wave * 1280;
#pragma unroll
        for (int j = 0; j < 4; ++j) {
            const int nn0 = bn * 128 + wc + j * 16 + hk * 4;
            const float4 b4 = *(const float4*)&pb[nn0];
#pragma unroll
            for (int i = 0; i < 4; ++i) {
                const int tk = i * 16 + ln;
                float4 o4;
                o4.x = acc[j][i][0] + b4.x;
                o4.y = acc[j][i][1] + b4.y;
                o4.z = acc[j][i][2] + b4.z;
                o4.w = acc[j][i][3] + b4.w;
                *(float4*)&epf[tk * 20 + hk * 4] = o4;
            }
            const int nnb = bn * 128 + wc + j * 16;
#pragma unroll
            for (int rr = 0; rr < 4; ++rr) {
                const int li = rr * 64 + lane;
                const int tk = li >> 2, c4 = (li & 3) * 4;
                float4 v4 = *(const float4*)&epf[tk * 20 + c4];
                *(float4*)(out + (size_t)(bm * 128 + wr + tk) * NCOLS + nnb + c4) = v4;
            }
        }
    } else {
        const int which = bn >> 2;             // 0=q, 1=k, 2=v
        const int bb = bm * 2;                 // tile spans windows bb, bb+1
        const size_t winbase = (size_t)((bb + (wr >> 6)) * 16);
        unsigned short* ep = smem + wave * 2560;
        if (which < 2) {
            // swapped: regs = 4 consecutive d-channels at one token
            kloop128<true>(Ab, Bb, smem, t, wave, ln, hk, wr, wc, acc);
            unsigned short* dst0 = (which == 0) ? qb : kb;
            // region [64 tok][40 shorts] (32 used): conflict-free writes
#pragma unroll
            for (int H = 0; H < 2; ++H) {
#pragma unroll
                for (int j2 = 0; j2 < 2; ++j2) {
                    const int j = H * 2 + j2;
                    const int rem0 = (bn * 128 + wc + j * 16 + hk * 4) & 511;
                    float4 b4 = {0.f, 0.f, 0.f, 0.f};
                    if (which == 0) b4 = *(const float4*)&bq[rem0];
                    const int ch0 = j2 * 16 + hk * 4;
#pragma unroll
                    for (int i = 0; i < 4; ++i) {
                        const int tk = i * 16 + ln;
                        ushort4 pk;
                        pk.x = f2bf(acc[j][i][0] + b4.x);
                        pk.y = f2bf(acc[j][i][1] + b4.y);
                        pk.z = f2bf(acc[j][i][2] + b4.z);
                        pk.w = f2bf(acc[j][i][3] + b4.w);
                        *(ushort4*)&ep[tk * 40 + ch0] = pk;
                    }
                }
                const int remH = (bn * 128 + wc + H * 32) & 511;
                const size_t Dq = (winbase + (remH >> 5)) * 2048;
#pragma unroll
                for (int rr = 0; rr < 4; ++rr) {      // 1KB contiguous / wave-instr
                    const int li = rr * 64 + lane;
                    const int tk = li >> 2, c8 = (li & 3) * 8;
                    s16x8 val = *(const s16x8*)&ep[tk * 40 + c8];
                    *(s16x8*)(dst0 + Dq + tk * 32 + c8) = val;
                }
            }
        } else {
            // normal: regs = 4 consecutive tokens at one d-channel -> v^T
            kloop128<false>(Ab, Bb, smem, t, wave, ln, hk, wr, wc, acc);
            // region [32 ch][72 shorts] (64 used)
#pragma unroll
            for (int H = 0; H < 2; ++H) {
#pragma unroll
                for (int j2 = 0; j2 < 2; ++j2) {
                    const int j = H * 2 + j2;
                    const int rem = (bn * 128 + wc + j * 16 + ln) & 511;
                    const float bias = bv[rem];
                    const int ch = j2 * 16 + ln;
#pragma unroll
                    for (int i = 0; i < 4; ++i) {
                        const int tk = i * 16 + hk * 4;
                        ushort4 pk;
                        pk.x = f2bf(acc[i][j][0] + bias);
                        pk.y = f2bf(acc[i][j][1] + bias);
                        pk.z = f2bf(acc[i][j][2] + bias);
                        pk.w = f2bf(acc[i][j][3] + bias);
                        *(ushort4*)&ep[ch * 72 + tk] = pk;
                    }
                }
                const int remH = (bn * 128 + wc + H * 32) & 511;
                const size_t Dv = (winbase + (remH >> 5)) * 2048;
#pragma unroll
                for (int rr = 0; rr < 4; ++rr) {      // 1KB contiguous / wave-instr
                    const int li = rr * 64 + lane;
                    const int dd = li >> 3, t8 = (li & 7) * 8;
                    s16x8 val = *(const s16x8*)&ep[dd * 72 + t8];
                    *(s16x8*)(vtb + Dv + dd * 64 + t8) = val;
                }
            }
        }
    }
}

// ---------- phase 4: attention, one block per (b, head) ----------
__global__ __launch_bounds__(256) void attn_kernel(
    const unsigned short* __restrict__ qbuf, const unsigned short* __restrict__ kbuf,
    const unsigned short* __restrict__ vtbuf, const float* __restrict__ rpb,
    const float* __restrict__ mask, unsigned short* __restrict__ aout) {
    __shared__ __align__(16) unsigned short ql[64 * 32];   // Q [tok][d]
    __shared__ __align__(16) unsigned short kl[64 * 32];   // K [tok][d]
    __shared__ __align__(16) unsigned short vl[32 * 64];   // V^T [d][tok]
    __shared__ __align__(16) unsigned short plds[64 * 72]; // P bf16, padded stride

    const int bh = blockIdx.x;
    const int b = bh >> 4, head = bh & 15;
    const int wmask = b & 255;               // window index = b % NW
    const int t = threadIdx.x, wave = t >> 6, lane = t & 63;
    const int ln = lane & 15, hk = lane >> 4;

    const size_t base = (size_t)bh * 2048;
    gload16(qbuf + base + t * 8, &ql[wave * 512]);
    gload16(kbuf + base + t * 8, &kl[wave * 512]);
    gload16(vtbuf + base + t * 8, &vl[wave * 512]);
    __syncthreads();

    // S = Q K^T : wave handles rows [16*wave, 16*wave+16)
    const f32x4 zero = {0.f, 0.f, 0.f, 0.f};
    s16x8 aq = *(const s16x8*)&ql[(wave * 16 + ln) * 32 + hk * 8];
    f32x4 sc[4];
#pragma unroll
    for (int j = 0; j < 4; ++j) {
        s16x8 bk = *(const s16x8*)&kl[(j * 16 + ln) * 32 + hk * 8];
        sc[j] = __builtin_amdgcn_mfma_f32_16x16x32_bf16(aq, bk, zero, 0, 0, 0);
    }

    const float scale = 0.17677669529663687f;  // 32^-0.5
    const float* rpb_h = rpb + head * 4096;
    const float* msk = mask + wmask * 4096;

    float p[4][4];
#pragma unroll
    for (int r = 0; r < 4; ++r) {
        const int i = wave * 16 + hk * 4 + r;
        float v[4], m = -1e30f;
#pragma unroll
        for (int j = 0; j < 4; ++j) {
            const int c = j * 16 + ln;
            v[j] = sc[j][r] * scale + rpb_h[i * 64 + c] + msk[i * 64 + c];
            m = fmaxf(m, v[j]);
        }
        for (int off = 1; off < 16; off <<= 1) m = fmaxf(m, __shfl_xor(m, off));
        float s = 0.f;
#pragma unroll
        for (int j = 0; j < 4; ++j) { v[j] = __expf(v[j] - m); s += v[j]; }
        for (int off = 1; off < 16; off <<= 1) s += __shfl_xor(s, off);
        const float inv = 1.f / s;
#pragma unroll
        for (int j = 0; j < 4; ++j) p[r][j] = v[j] * inv;
    }
    // P rows are wave-private (write rows wave*16+hk*4+r, read rows
    // wave*16+ln) -> no barrier needed; in-wave lgkmcnt orders the LDS ops.
#pragma unroll
    for (int r = 0; r < 4; ++r)
#pragma unroll
        for (int j = 0; j < 4; ++j)
            plds[(wave * 16 + hk * 4 + r) * 72 + j * 16 + ln] = f2bf(p[r][j]);

    // O^T = (P V)^T via swapped operands: regs = 4 consecutive d at one token
    f32x4 o2[2] = {zero, zero};
#pragma unroll
    for (int kt = 0; kt < 2; ++kt) {
        s16x8 ap = *(const s16x8*)&plds[(wave * 16 + ln) * 72 + kt * 32 + hk * 8];
#pragma unroll
        for (int nt = 0; nt < 2; ++nt) {
            s16x8 bvf = *(const s16x8*)&vl[(nt * 16 + ln) * 64 + kt * 32 + hk * 8];
            o2[nt] = __builtin_amdgcn_mfma_f32_16x16x32_bf16(bvf, ap, o2[nt], 0, 0, 0);
        }
    }
    // coalesce aout stores through a wave-private slice of plds
    unsigned short* ep = plds + wave * 1152;   // rows wave*16.. (own rows)
#pragma unroll
    for (int nt = 0; nt < 2; ++nt) {
        ushort4 pk;
        pk.x = f2bf(o2[nt][0]); pk.y = f2bf(o2[nt][1]);
        pk.z = f2bf(o2[nt][2]); pk.w = f2bf(o2[nt][3]);
        *(ushort4*)&ep[ln * 40 + nt * 16 + hk * 4] = pk;
    }
    const int tk = lane >> 2, c8 = (lane & 3) * 8;
    s16x8 val = *(const s16x8*)&ep[tk * 40 + c8];
    *(s16x8*)(aout + ((size_t)(b * 64 + wave * 16 + tk)) * 512 + head * 32 + c8) = val;
}

// ---------- launcher ----------
extern "C" void kernel_launch(void* const* d_in, const int* in_sizes, int n_in,
                              void* d_out, int out_size, void* d_ws, size_t ws_size,
                              hipStream_t stream) {
    const float* x      = (const float*)d_in[0];
    const float* mask   = (const float*)d_in[1];
    const float* qkv_w  = (const float*)d_in[2];
    const float* q_bias = (const float*)d_in[3];
    const float* v_bias = (const float*)d_in[4];
    const float* rpb_t  = (const float*)d_in[5];
    const float* proj_w = (const float*)d_in[6];
    const float* proj_b = (const float*)d_in[7];
    const int*   rel    = (const int*)d_in[8];
    float* out = (float*)d_out;

    char* ws = (char*)d_ws;
    unsigned short* xbf   = (unsigned short*)ws;                  // 128 MiB, reused as attn_out
    unsigned short* qbuf  = (unsigned short*)(ws + 0x08000000);   // 128 MiB
    unsigned short* kbuf  = (unsigned short*)(ws + 0x10000000);   // 128 MiB
    unsigned short* vtbuf = (unsigned short*)(ws + 0x18000000);   // 128 MiB
    unsigned short* wqkv  = (unsigned short*)(ws + 0x20000000);   // 1.5 MiB
    unsigned short* wproj = (unsigned short*)(ws + 0x20180000);   // 0.5 MiB
    float*          rpb   = (float*)(ws + 0x20200000);            // 0.25 MiB
    unsigned short* aout  = xbf;

    cast_bf16_kernel<<<65536, 256, 0, stream>>>(x, xbf, 16777216);
    cast_bf16_kernel<<<768, 256, 0, stream>>>(qkv_w, wqkv, 196608);
    cast_bf16_kernel<<<256, 256, 0, stream>>>(proj_w, wproj, 65536);
    rpb_kernel<<<64, 64, 0, stream>>>(rpb_t, rel, rpb);

    gemm_bt<0, 1536><<<1024 * 12, 256, 0, stream>>>(
        xbf, wqkv, q_bias, v_bias, qbuf, kbuf, vtbuf, nullptr, nullptr);

    attn_kernel<<<32768, 256, 0, stream>>>(qbuf, kbuf, vtbuf, rpb, mask, aout);

    gemm_bt<1, 512><<<1024 * 4, 256, 0, stream>>>(
        aout, wproj, nullptr, nullptr, nullptr, nullptr, nullptr, proj_b, out);
}

// Round 4
// 1010.387 us; speedup vs baseline: 1.1252x; 1.0019x over previous
//
#include <hip/hip_runtime.h>

typedef short s16x8 __attribute__((ext_vector_type(8)));
typedef float f32x4 __attribute__((ext_vector_type(4)));

// ---------- helpers ----------
__device__ __forceinline__ unsigned short f2bf(float f) {
    unsigned int u = __builtin_bit_cast(unsigned int, f);
    u += 0x7fffu + ((u >> 16) & 1u);           // round-to-nearest-even
    return (unsigned short)(u >> 16);
}

__device__ __forceinline__ void gload16(const void* g, void* l) {
    __builtin_amdgcn_global_load_lds(
        (const __attribute__((address_space(1))) unsigned int*)g,
        (__attribute__((address_space(3))) unsigned int*)l,
        16, 0, 0);
}

// ---------- phase 1: fp32 -> bf16 casts ----------
__global__ void cast_bf16_kernel(const float* __restrict__ src,
                                 unsigned short* __restrict__ dst, int n4) {
    int i = blockIdx.x * 256 + threadIdx.x;
    if (i >= n4) return;
    float4 v = ((const float4*)src)[i];
    ushort4 o;
    o.x = f2bf(v.x); o.y = f2bf(v.y); o.z = f2bf(v.z); o.w = f2bf(v.w);
    ((ushort4*)dst)[i] = o;
}

// ---------- phase 2: gather relative position bias rpb[h][64][64] ----------
__global__ void rpb_kernel(const float* __restrict__ table,
                           const int* __restrict__ rel,
                           float* __restrict__ rpb) {
    int t = blockIdx.x * 64 + threadIdx.x;     // 0..4095  (i*64+j)
    int idx = rel[t];
#pragma unroll
    for (int h = 0; h < 16; ++h)
        rpb[h * 4096 + t] = table[idx * 16 + h];
}

// ---------- K-loop building blocks ----------
// LDS tile [128 row][4 granule][8 shorts]; granule slot holds global granule
// (slot ^ key(row)), key(row) = (row>>1)&3.  Source-permuted (dest linear,
// required by global_load_lds); read side XORs the same key ->
// fragment reads spread over 8 start-banks = 2-way = free.
__device__ __forceinline__ void stage_step(const unsigned short* __restrict__ Ab,
                                           const unsigned short* __restrict__ Bb,
                                           unsigned short* base, int wave,
                                           size_t gA0, size_t gA1, int k0) {
    gload16(Ab + gA0 + k0, &base[wave * 512]);
    gload16(Ab + gA1 + k0, &base[2048 + wave * 512]);
    gload16(Bb + gA0 + k0, &base[4096 + wave * 512]);
    gload16(Bb + gA1 + k0, &base[6144 + wave * 512]);
}

template <bool SW>
__device__ __forceinline__ void mfma_step(const unsigned short* base, int ln, int hk,
                                          int wr, int wc, f32x4 (&acc)[4][4]) {
    const unsigned short* Al = base;
    const unsigned short* Bl = base + 4096;
    const int sl = hk ^ ((ln >> 1) & 3);       // swizzled granule slot
    s16x8 af[4], bf[4];
#pragma unroll
    for (int i = 0; i < 4; ++i)
        af[i] = *(const s16x8*)&Al[(wr + i * 16 + ln) * 32 + sl * 8];
#pragma unroll
    for (int j = 0; j < 4; ++j)
        bf[j] = *(const s16x8*)&Bl[(wc + j * 16 + ln) * 32 + sl * 8];
#pragma unroll
    for (int i = 0; i < 4; ++i)
#pragma unroll
        for (int j = 0; j < 4; ++j) {
            if constexpr (SW)
                acc[j][i] = __builtin_amdgcn_mfma_f32_16x16x32_bf16(bf[j], af[i], acc[j][i], 0, 0, 0);
            else
                acc[i][j] = __builtin_amdgcn_mfma_f32_16x16x32_bf16(af[i], bf[j], acc[i][j], 0, 0, 0);
        }
}

// Double-buffered 128x128 K-loop (K=512, BK=32): stage tile t+1 while
// computing tile t; ONE __syncthreads per K-step (T3 minimum-2-phase).
template <bool SW>
__device__ __forceinline__ void kloop128(const unsigned short* __restrict__ Ab,
                                         const unsigned short* __restrict__ Bb,
                                         unsigned short* smem,
                                         int t, int wave, int ln, int hk,
                                         int wr, int wc, f32x4 (&acc)[4][4]) {
    const int row = t >> 2, cg = t & 3;
    const int cgs = cg ^ ((t >> 3) & 3);       // source granule permute
    const size_t gA0 = (size_t)row * 512 + cgs * 8;
    const size_t gA1 = (size_t)(row + 64) * 512 + cgs * 8;   // same key (row+64)
    unsigned short* b0 = smem;          // tiles A,B for even steps
    unsigned short* b1 = smem + 8192;   // tiles A,B for odd steps

    stage_step(Ab, Bb, b0, wave, gA0, gA1, 0);
    __syncthreads();
    for (int k0 = 0; k0 < 512; k0 += 64) {
        stage_step(Ab, Bb, b1, wave, gA0, gA1, k0 + 32);
        mfma_step<SW>(b0, ln, hk, wr, wc, acc);
        __syncthreads();
        if (k0 + 64 < 512)
            stage_step(Ab, Bb, b0, wave, gA0, gA1, k0 + 64);
        mfma_step<SW>(b1, ln, hk, wr, wc, acc);
        __syncthreads();
    }
}

// ---------- GEMM C = A(MxK) * B(NxK)^T, bf16 in, fp32 acc ----------
template <int MODE, int NCOLS>
__global__ __launch_bounds__(256) void gemm_bt(
    const unsigned short* __restrict__ A, const unsigned short* __restrict__ B,
    const float* __restrict__ bq, const float* __restrict__ bv,
    unsigned short* __restrict__ qb, unsigned short* __restrict__ kb,
    unsigned short* __restrict__ vtb,
    const float* __restrict__ pb, float* __restrict__ out) {
    // 32KB: double-buffered staging (2 x 8192 shorts); epilogue reuses it as
    // 4 x 2560-short wave-private repack regions (safe: post final barrier,
    // regions wave-private).
    __shared__ __align__(16) unsigned short smem[16384];

    constexpr int NBN = NCOLS / 128;
    // XCD-chunked swizzle (grid % 8 == 0): all bn-tiles of a bm on one XCD
    const unsigned int cpx = gridDim.x >> 3;
    const unsigned int wg = (blockIdx.x & 7u) * cpx + (blockIdx.x >> 3);
    const int bm = wg / NBN;
    const int bn = wg % NBN;
    const int t = threadIdx.x;
    const int wave = t >> 6, lane = t & 63;
    const int ln = lane & 15, hk = lane >> 4;
    const int wr = (wave >> 1) * 64, wc = (wave & 1) * 64;

    const f32x4 zero = {0.f, 0.f, 0.f, 0.f};
    f32x4 acc[4][4];
#pragma unroll
    for (int i = 0; i < 4; ++i)
#pragma unroll
        for (int j = 0; j < 4; ++j) acc[i][j] = zero;

    const unsigned short* Ab = A + (size_t)bm * 128 * 512;
    const unsigned short* Bb = B + (size_t)bn * 128 * 512;

    if constexpr (MODE == 1) {
        kloop128<true>(Ab, Bb, smem, t, wave, ln, hk, wr, wc, acc);
        // per-wave fp32 region [64 tok][20 words] (pad 16->20 kills conflicts)
        float* epf = (float*)smem + wave * 1280;
#pragma unroll
        for (int j = 0; j < 4; ++j) {
            const int nn0 = bn * 128 + wc + j * 16 + hk * 4;
            const float4 b4 = *(const float4*)&pb[nn0];
#pragma unroll
            for (int i = 0; i < 4; ++i) {
                const int tk = i * 16 + ln;
                float4 o4;
                o4.x = acc[j][i][0] + b4.x;
                o4.y = acc[j][i][1] + b4.y;
                o4.z = acc[j][i][2] + b4.z;
                o4.w = acc[j][i][3] + b4.w;
                *(float4*)&epf[tk * 20 + hk * 4] = o4;
            }
            const int nnb = bn * 128 + wc + j * 16;
#pragma unroll
            for (int rr = 0; rr < 4; ++rr) {
                const int li = rr * 64 + lane;
                const int tk = li >> 2, c4 = (li & 3) * 4;
                float4 v4 = *(const float4*)&epf[tk * 20 + c4];
                *(float4*)(out + (size_t)(bm * 128 + wr + tk) * NCOLS + nnb + c4) = v4;
            }
        }
    } else {
        const int which = bn >> 2;             // 0=q, 1=k, 2=v
        const int bb = bm * 2;                 // tile spans windows bb, bb+1
        const size_t winbase = (size_t)((bb + (wr >> 6)) * 16);
        unsigned short* ep = smem + wave * 2560;
        if (which < 2) {
            // swapped: regs = 4 consecutive d-channels at one token
            kloop128<true>(Ab, Bb, smem, t, wave, ln, hk, wr, wc, acc);
            unsigned short* dst0 = (which == 0) ? qb : kb;
            // region [64 tok][40 shorts] (32 used): conflict-free writes
#pragma unroll
            for (int H = 0; H < 2; ++H) {
#pragma unroll
                for (int j2 = 0; j2 < 2; ++j2) {
                    const int j = H * 2 + j2;
                    const int rem0 = (bn * 128 + wc + j * 16 + hk * 4) & 511;
                    float4 b4 = {0.f, 0.f, 0.f, 0.f};
                    if (which == 0) b4 = *(const float4*)&bq[rem0];
                    const int ch0 = j2 * 16 + hk * 4;
#pragma unroll
                    for (int i = 0; i < 4; ++i) {
                        const int tk = i * 16 + ln;
                        ushort4 pk;
                        pk.x = f2bf(acc[j][i][0] + b4.x);
                        pk.y = f2bf(acc[j][i][1] + b4.y);
                        pk.z = f2bf(acc[j][i][2] + b4.z);
                        pk.w = f2bf(acc[j][i][3] + b4.w);
                        *(ushort4*)&ep[tk * 40 + ch0] = pk;
                    }
                }
                const int remH = (bn * 128 + wc + H * 32) & 511;
                const size_t Dq = (winbase + (remH >> 5)) * 2048;
#pragma unroll
                for (int rr = 0; rr < 4; ++rr) {      // 1KB contiguous / wave-instr
                    const int li = rr * 64 + lane;
                    const int tk = li >> 2, c8 = (li & 3) * 8;
                    s16x8 val = *(const s16x8*)&ep[tk * 40 + c8];
                    *(s16x8*)(dst0 + Dq + tk * 32 + c8) = val;
                }
            }
        } else {
            // normal: regs = 4 consecutive tokens at one d-channel -> v^T
            kloop128<false>(Ab, Bb, smem, t, wave, ln, hk, wr, wc, acc);
            // region [32 ch][72 shorts] (64 used)
#pragma unroll
            for (int H = 0; H < 2; ++H) {
#pragma unroll
                for (int j2 = 0; j2 < 2; ++j2) {
                    const int j = H * 2 + j2;
                    const int rem = (bn * 128 + wc + j * 16 + ln) & 511;
                    const float bias = bv[rem];
                    const int ch = j2 * 16 + ln;
#pragma unroll
                    for (int i = 0; i < 4; ++i) {
                        const int tk = i * 16 + hk * 4;
                        ushort4 pk;
                        pk.x = f2bf(acc[i][j][0] + bias);
                        pk.y = f2bf(acc[i][j][1] + bias);
                        pk.z = f2bf(acc[i][j][2] + bias);
                        pk.w = f2bf(acc[i][j][3] + bias);
                        *(ushort4*)&ep[ch * 72 + tk] = pk;
                    }
                }
                const int remH = (bn * 128 + wc + H * 32) & 511;
                const size_t Dv = (winbase + (remH >> 5)) * 2048;
#pragma unroll
                for (int rr = 0; rr < 4; ++rr) {      // 1KB contiguous / wave-instr
                    const int li = rr * 64 + lane;
                    const int dd = li >> 3, t8 = (li & 7) * 8;
                    s16x8 val = *(const s16x8*)&ep[dd * 72 + t8];
                    *(s16x8*)(vtb + Dv + dd * 64 + t8) = val;
                }
            }
        }
    }
}

// ---------- phase 4: attention, one block per (b, head) ----------
__global__ __launch_bounds__(256) void attn_kernel(
    const unsigned short* __restrict__ qbuf, const unsigned short* __restrict__ kbuf,
    const unsigned short* __restrict__ vtbuf, const float* __restrict__ rpb,
    const float* __restrict__ mask, unsigned short* __restrict__ aout) {
    __shared__ __align__(16) unsigned short ql[64 * 32];   // Q [tok][4 gr][8]
    __shared__ __align__(16) unsigned short kl[64 * 32];   // K [tok][4 gr][8]
    __shared__ __align__(16) unsigned short vl[32 * 64];   // V^T [d][8 gr][8]
    __shared__ __align__(16) unsigned short plds[64 * 72]; // P bf16, padded stride

    const int bh = blockIdx.x;
    const int b = bh >> 4, head = bh & 15;
    const int wmask = b & 255;               // window index = b % NW
    const int t = threadIdx.x, wave = t >> 6, lane = t & 63;
    const int ln = lane & 15, hk = lane >> 4;

    const size_t base = (size_t)bh * 2048;
    // source-permuted staging (dest stays linear): q/k key=(row>>1)&3,
    // v key = row&7 (128B rows need the full 3-bit key)
    {
        const int r4 = t >> 2, c4 = t & 3;
        const int qs = c4 ^ ((t >> 3) & 3);
        gload16(qbuf + base + r4 * 32 + qs * 8, &ql[wave * 512]);
        gload16(kbuf + base + r4 * 32 + qs * 8, &kl[wave * 512]);
        const int r8 = t >> 3, c8v = t & 7;
        const int vs = c8v ^ (r8 & 7);
        gload16(vtbuf + base + r8 * 64 + vs * 8, &vl[wave * 512]);
    }
    __syncthreads();

    // S = Q K^T : wave handles rows [16*wave, 16*wave+16)
    const f32x4 zero = {0.f, 0.f, 0.f, 0.f};
    const int slq = hk ^ ((ln >> 1) & 3);     // q/k swizzled slot
    s16x8 aq = *(const s16x8*)&ql[(wave * 16 + ln) * 32 + slq * 8];
    f32x4 sc[4];
#pragma unroll
    for (int j = 0; j < 4; ++j) {
        s16x8 bk = *(const s16x8*)&kl[(j * 16 + ln) * 32 + slq * 8];
        sc[j] = __builtin_amdgcn_mfma_f32_16x16x32_bf16(aq, bk, zero, 0, 0, 0);
    }

    const float scale = 0.17677669529663687f;  // 32^-0.5
    const float* rpb_h = rpb + head * 4096;
    const float* msk = mask + wmask * 4096;

    float p[4][4];
#pragma unroll
    for (int r = 0; r < 4; ++r) {
        const int i = wave * 16 + hk * 4 + r;
        float v[4], m = -1e30f;
#pragma unroll
        for (int j = 0; j < 4; ++j) {
            const int c = j * 16 + ln;
            v[j] = sc[j][r] * scale + rpb_h[i * 64 + c] + msk[i * 64 + c];
            m = fmaxf(m, v[j]);
        }
        for (int off = 1; off < 16; off <<= 1) m = fmaxf(m, __shfl_xor(m, off));
        float s = 0.f;
#pragma unroll
        for (int j = 0; j < 4; ++j) { v[j] = __expf(v[j] - m); s += v[j]; }
        for (int off = 1; off < 16; off <<= 1) s += __shfl_xor(s, off);
        const float inv = 1.f / s;
#pragma unroll
        for (int j = 0; j < 4; ++j) p[r][j] = v[j] * inv;
    }
    // P rows are wave-private (write rows wave*16+hk*4+r, read rows
    // wave*16+ln) -> no barrier needed; in-wave lgkmcnt orders the LDS ops.
#pragma unroll
    for (int r = 0; r < 4; ++r)
#pragma unroll
        for (int j = 0; j < 4; ++j)
            plds[(wave * 16 + hk * 4 + r) * 72 + j * 16 + ln] = f2bf(p[r][j]);

    // O^T = (P V)^T via swapped operands: regs = 4 consecutive d at one token
    f32x4 o2[2] = {zero, zero};
#pragma unroll
    for (int kt = 0; kt < 2; ++kt) {
        s16x8 ap = *(const s16x8*)&plds[(wave * 16 + ln) * 72 + kt * 32 + hk * 8];
#pragma unroll
        for (int nt = 0; nt < 2; ++nt) {
            const int vsl = (kt * 4 + hk) ^ (ln & 7);   // v swizzled slot
            s16x8 bvf = *(const s16x8*)&vl[(nt * 16 + ln) * 64 + vsl * 8];
            o2[nt] = __builtin_amdgcn_mfma_f32_16x16x32_bf16(bvf, ap, o2[nt], 0, 0, 0);
        }
    }
    // coalesce aout stores through a wave-private slice of plds
    unsigned short* ep = plds + wave * 1152;   // rows wave*16.. (own rows)
#pragma unroll
    for (int nt = 0; nt < 2; ++nt) {
        ushort4 pk;
        pk.x = f2bf(o2[nt][0]); pk.y = f2bf(o2[nt][1]);
        pk.z = f2bf(o2[nt][2]); pk.w = f2bf(o2[nt][3]);
        *(ushort4*)&ep[ln * 40 + nt * 16 + hk * 4] = pk;
    }
    const int tk = lane >> 2, c8 = (lane & 3) * 8;
    s16x8 val = *(const s16x8*)&ep[tk * 40 + c8];
    *(s16x8*)(aout + ((size_t)(b * 64 + wave * 16 + tk)) * 512 + head * 32 + c8) = val;
}

// ---------- launcher ----------
extern "C" void kernel_launch(void* const* d_in, const int* in_sizes, int n_in,
                              void* d_out, int out_size, void* d_ws, size_t ws_size,
                              hipStream_t stream) {
    const float* x      = (const float*)d_in[0];
    const float* mask   = (const float*)d_in[1];
    const float* qkv_w  = (const float*)d_in[2];
    const float* q_bias = (const float*)d_in[3];
    const float* v_bias = (const float*)d_in[4];
    const float* rpb_t  = (const float*)d_in[5];
    const float* proj_w = (const float*)d_in[6];
    const float* proj_b = (const float*)d_in[7];
    const int*   rel    = (const int*)d_in[8];
    float* out = (float*)d_out;

    char* ws = (char*)d_ws;
    unsigned short* xbf   = (unsigned short*)ws;                  // 128 MiB, reused as attn_out
    unsigned short* qbuf  = (unsigned short*)(ws + 0x08000000);   // 128 MiB
    unsigned short* kbuf  = (unsigned short*)(ws + 0x10000000);   // 128 MiB
    unsigned short* vtbuf = (unsigned short*)(ws + 0x18000000);   // 128 MiB
    unsigned short* wqkv  = (unsigned short*)(ws + 0x20000000);   // 1.5 MiB
    unsigned short* wproj = (unsigned short*)(ws + 0x20180000);   // 0.5 MiB
    float*          rpb   = (float*)(ws + 0x20200000);            // 0.25 MiB
    unsigned short* aout  = xbf;

    cast_bf16_kernel<<<65536, 256, 0, stream>>>(x, xbf, 16777216);
    cast_bf16_kernel<<<768, 256, 0, stream>>>(qkv_w, wqkv, 196608);
    cast_bf16_kernel<<<256, 256, 0, stream>>>(proj_w, wproj, 65536);
    rpb_kernel<<<64, 64, 0, stream>>>(rpb_t, rel, rpb);

    gemm_bt<0, 1536><<<1024 * 12, 256, 0, stream>>>(
        xbf, wqkv, q_bias, v_bias, qbuf, kbuf, vtbuf, nullptr, nullptr);

    attn_kernel<<<32768, 256, 0, stream>>>(qbuf, kbuf, vtbuf, rpb, mask, aout);

    gemm_bt<1, 512><<<1024 * 4, 256, 0, stream>>>(
        aout, wproj, nullptr, nullptr, nullptr, nullptr, nullptr, proj_b, out);
}